// Round 2
// baseline (766.530 us; speedup 1.0000x reference)
//
#include <hip/hip_runtime.h>
#include <hip/hip_bf16.h>

#define N_    32
#define T_    1600
#define C_    1024
#define S_    200
#define L_    401       // 2*S+1
#define LP_   512       // padded to 64*8
#define BLANK_ 4
#define NEG_  (-1.0e30f)
#define L2E_  1.44269504088896341f
#define LN2_  0.69314718055994531f
#define DPF   8

#if __has_builtin(__builtin_amdgcn_exp2f)
#define EXP2(x) __builtin_amdgcn_exp2f(x)
#else
#define EXP2(x) exp2f(x)
#endif
#if __has_builtin(__builtin_amdgcn_logf)
#define LOG2(x) __builtin_amdgcn_logf(x)
#else
#define LOG2(x) log2f(x)
#endif

// Kernel 1: per (n,t) row: softmax denom over C, then write
// G[n][t][l] = log2 p(ext[n][l]) for l<=400, 0 for pad.
// Pad positions are feed-forward-only in k_ctc (never read out, never wrap
// back — lane-0 override below), so pad value is semantically dead.
__global__ __launch_bounds__(256)
void k_softmax_gather(const float* __restrict__ logits,
                      const int* __restrict__ targets,
                      float* __restrict__ G) {
  const int t = blockIdx.x;
  const int n = blockIdx.y;
  const int tid = threadIdx.x;
  const float* row = logits + ((size_t)n * T_ + t) * C_;
  __shared__ float sh[C_];
  __shared__ float red[16];

  float4 v = reinterpret_cast<const float4*>(row)[tid];
  reinterpret_cast<float4*>(sh)[tid] = v;

  float mx = fmaxf(fmaxf(v.x, v.y), fmaxf(v.z, v.w));
#pragma unroll
  for (int i = 1; i < 64; i <<= 1) mx = fmaxf(mx, __shfl_xor(mx, i));
  if ((tid & 63) == 0) red[tid >> 6] = mx;
  __syncthreads();
  float M = fmaxf(fmaxf(red[0], red[1]), fmaxf(red[2], red[3]));

  float s = __expf(v.x - M) + __expf(v.y - M) + __expf(v.z - M) + __expf(v.w - M);
#pragma unroll
  for (int i = 1; i < 64; i <<= 1) s += __shfl_xor(s, i);
  if ((tid & 63) == 0) red[8 + (tid >> 6)] = s;
  __syncthreads();
  float sum = red[8] + red[9] + red[10] + red[11];

  // log2 p(c) = x[c]*L2E - (M*L2E + log2(sum))
  float off = M * L2E_ + LOG2(sum);

  float* go = G + ((size_t)n * T_ + t) * LP_;
  for (int l = tid; l < LP_; l += 256) {
    float val = 0.0f;
    if (l <= 2 * S_) {
      int c = (l & 1) ? targets[n * S_ + ((l - 1) >> 1)] : BLANK_;
      val = sh[c] * L2E_ - off;
    }
    go[l] = val;
  }
}

// Kernel 2: log-space CTC forward. One wave per sequence; lane owns 8
// contiguous extended-label positions l = 8*lane + j.
__global__ __launch_bounds__(64)
void k_ctc(const float* __restrict__ G,
           const int* __restrict__ targets,
           const int* __restrict__ in_len,
           const int* __restrict__ tgt_len,
           float* __restrict__ nll_out) {
  const int n = blockIdx.x;
  const int lane = threadIdx.x;
  const int Tn = in_len[n];
  const float* g = G + (size_t)n * T_ * LP_;

  // skip bias: 0 if skip transition allowed at l, else NEG (additive mask)
  float sb[8];
#pragma unroll
  for (int j = 0; j < 8; ++j) {
    int l = lane * 8 + j;
    float b = NEG_;
    if ((l & 1) && l >= 3 && l <= 2 * S_) {
      int m = (l - 1) >> 1;
      b = (targets[n * S_ + m] != targets[n * S_ + m - 1]) ? 0.0f : NEG_;
    }
    sb[j] = b;
  }

  // alpha at t=0: only l=0,1 live
  float a[8];
#pragma unroll
  for (int j = 0; j < 8; ++j) a[j] = NEG_;
  if (lane == 0) { a[0] = g[0]; a[1] = g[1]; }

  // register prefetch ring, depth DPF
  const float* gl = g + lane * 8;
  float4 bA[DPF], bB[DPF];
#pragma unroll
  for (int d = 0; d < DPF; ++d) {
    int tt = 1 + d; if (tt > T_ - 1) tt = T_ - 1;
    bA[d] = *reinterpret_cast<const float4*>(gl + (size_t)tt * LP_);
    bB[d] = *reinterpret_cast<const float4*>(gl + (size_t)tt * LP_ + 4);
  }

  const int src = (lane + 63) & 63;  // lane-1
  int t = 1;
  bool run = true;
  while (run) {
#pragma unroll
    for (int d = 0; d < DPF; ++d) {
      if (t >= Tn) { run = false; break; }
      float up7 = __shfl(a[7], src);   // alpha[l-1] for j=0
      float up6 = __shfl(a[6], src);   // alpha[l-2] for j=0
      // CRITICAL: lane 0 has no predecessor — without this override it reads
      // lane 63 (pad alpha, G=0 => prob-1 self-loop) and recycles mass into
      // l=0, inflating all alphas (R1 bug: out 17.9 vs ref 77.5).
      if (lane == 0) { up7 = NEG_; up6 = NEG_; }
      float gv[8] = {bA[d].x, bA[d].y, bA[d].z, bA[d].w,
                     bB[d].x, bB[d].y, bB[d].z, bB[d].w};
      float na[8];
#pragma unroll
      for (int j = 0; j < 8; ++j) {
        float aj = a[j];
        float b = (j == 0) ? up7 : a[j - 1];
        float c = ((j == 0) ? up6 : (j == 1) ? up7 : a[j - 2]) + sb[j];
        float m = fmaxf(fmaxf(aj, b), c);
        float e = EXP2(aj - m) + EXP2(b - m) + EXP2(c - m);
        na[j] = m + LOG2(e) + gv[j];
      }
#pragma unroll
      for (int j = 0; j < 8; ++j) a[j] = na[j];
      // refill this slot for step t+DPF (clamped; clamped rows never consumed)
      int tt = t + DPF; if (tt > T_ - 1) tt = T_ - 1;
      bA[d] = *reinterpret_cast<const float4*>(gl + (size_t)tt * LP_);
      bB[d] = *reinterpret_cast<const float4*>(gl + (size_t)tt * LP_ + 4);
      ++t;
    }
  }

  __shared__ float sa[LP_];
#pragma unroll
  for (int j = 0; j < 8; ++j) sa[lane * 8 + j] = a[j];
  __syncthreads();
  if (lane == 0) {
    int tl = tgt_len[n];
    float A1 = sa[2 * tl - 1];
    float A2 = sa[2 * tl];
    float m = fmaxf(A1, A2);
    float r = m + LOG2(EXP2(A1 - m) + EXP2(A2 - m));
    nll_out[n] = -r * LN2_;
  }
}

__global__ void k_final(const float* __restrict__ nll,
                        const int* __restrict__ tgt_len,
                        float* __restrict__ out) {
  int lane = threadIdx.x;
  float v = 0.0f;
  if (lane < N_) v = nll[lane] / (float)tgt_len[lane];
#pragma unroll
  for (int i = 1; i < 64; i <<= 1) v += __shfl_xor(v, i);
  if (lane == 0) out[0] = v * (1.0f / N_);
}

__global__ void k_sentinel(float* out) { out[0] = -12345.0f; }

extern "C" void kernel_launch(void* const* d_in, const int* in_sizes, int n_in,
                              void* d_out, int out_size, void* d_ws, size_t ws_size,
                              hipStream_t stream) {
  const float* logits = (const float*)d_in[0];
  const int* targets  = (const int*)d_in[1];
  const int* in_len   = (const int*)d_in[2];
  const int* tgt_len  = (const int*)d_in[3];
  float* out = (float*)d_out;

  size_t gbytes = (size_t)N_ * T_ * LP_ * sizeof(float);  // ~104.9 MB
  if (ws_size < gbytes + 256) {
    k_sentinel<<<1, 1, 0, stream>>>(out);
    return;
  }
  float* G = (float*)d_ws;
  float* nll = (float*)((char*)d_ws + gbytes);

  dim3 g1(T_, N_);
  k_softmax_gather<<<g1, 256, 0, stream>>>(logits, targets, G);
  k_ctc<<<N_, 64, 0, stream>>>(G, targets, in_len, tgt_len, nll);
  k_final<<<1, 64, 0, stream>>>(nll, tgt_len, out);
}

// Round 3
// 688.722 us; speedup vs baseline: 1.1130x; 1.1130x over previous
//
#include <hip/hip_runtime.h>
#include <hip/hip_bf16.h>

#define N_    32
#define T_    1600
#define C_    1024
#define S_    200
#define L_    401       // 2*S+1
#define LP_   512       // padded to 64*8
#define BLANK_ 4
#define LN2_  0.69314718055994531f
#define L2E_  1.44269504088896341f
#define DPF   8
#define ZMIN_  (-(1 << 24))   // exponent sentinel for alpha==0
#define SBIAS_ (-(1 << 26))   // skip-blocked exponent bias (ldexp clamps -> 0)

#if __has_builtin(__builtin_amdgcn_exp2f)
#define EXP2(x) __builtin_amdgcn_exp2f(x)
#else
#define EXP2(x) exp2f(x)
#endif
#if __has_builtin(__builtin_amdgcn_logf)
#define LOG2(x) __builtin_amdgcn_logf(x)
#else
#define LOG2(x) log2f(x)
#endif
#if __has_builtin(__builtin_amdgcn_ldexpf)
#define LDEXP(x,i) __builtin_amdgcn_ldexpf((x),(i))
#else
#define LDEXP(x,i) ldexpf((x),(i))
#endif

#if __has_builtin(__builtin_amdgcn_frexp_mantf) && __has_builtin(__builtin_amdgcn_frexp_expf)
#define FR_MANT(x) __builtin_amdgcn_frexp_mantf(x)
#define FR_EXP(x)  __builtin_amdgcn_frexp_expf(x)
#else
__device__ inline float FR_MANT(float x) { int e; return frexpf(x, &e); }
__device__ inline int   FR_EXP(float x)  { int e; frexpf(x, &e); return e; }
#endif

#if __has_builtin(__builtin_amdgcn_rcpf)
#define RCP(x) __builtin_amdgcn_rcpf(x)
#else
#define RCP(x) (1.0f / (x))
#endif

// Kernel 1: one wave per (n,t) row. Wave-shuffle softmax reduction (no block
// barriers), row staged in per-wave LDS, then gather ext-label classes and
// write LINEAR probabilities P[n][t][l] (0 for pads l>400).
__global__ __launch_bounds__(256)
void k_softmax_gather(const float* __restrict__ logits,
                      const int* __restrict__ targets,
                      float* __restrict__ P) {
  const int row  = blockIdx.x * 4 + (threadIdx.x >> 6);  // n*T_ + t
  const int lane = threadIdx.x & 63;
  const int wv   = threadIdx.x >> 6;
  const int n    = row / T_;
  const float* x = logits + (size_t)row * C_;
  __shared__ float sh[4][C_];

  float4 v[4];
#pragma unroll
  for (int i = 0; i < 4; ++i)
    v[i] = reinterpret_cast<const float4*>(x)[i * 64 + lane];

  float mx = v[0].x;
#pragma unroll
  for (int i = 0; i < 4; ++i)
    mx = fmaxf(mx, fmaxf(fmaxf(v[i].x, v[i].y), fmaxf(v[i].z, v[i].w)));
#pragma unroll
  for (int i = 1; i < 64; i <<= 1) mx = fmaxf(mx, __shfl_xor(mx, i));

  float s = 0.0f;
#pragma unroll
  for (int i = 0; i < 4; ++i) {
    s += EXP2((v[i].x - mx) * L2E_) + EXP2((v[i].y - mx) * L2E_)
       + EXP2((v[i].z - mx) * L2E_) + EXP2((v[i].w - mx) * L2E_);
  }
#pragma unroll
  for (int i = 1; i < 64; i <<= 1) s += __shfl_xor(s, i);
  float rz = RCP(s);

#pragma unroll
  for (int i = 0; i < 4; ++i)
    reinterpret_cast<float4*>(sh[wv])[i * 64 + lane] = v[i];
  __syncthreads();

  const int* tg = targets + n * S_;
  float* out = P + (size_t)row * LP_;
#pragma unroll
  for (int i = 0; i < 8; ++i) {
    int l = lane + i * 64;
    float p = 0.0f;
    if (l < L_) {
      int c = (l & 1) ? tg[(l - 1) >> 1] : BLANK_;
      p = EXP2((sh[wv][c] - mx) * L2E_) * rz;
    }
    out[l] = p;
  }
}

// Kernel 2: CTC forward in extended-range linear space: alpha = f * 2^e,
// f frexp-normalized float, e int32. logaddexp3+g becomes max3_i32 + 3 ldexp
// + 2 add + 1 mul + frexp renorm — zero transcendentals in the 1600-step loop.
__global__ __launch_bounds__(64)
void k_ctc(const float* __restrict__ P,
           const int* __restrict__ targets,
           const int* __restrict__ in_len,
           const int* __restrict__ tgt_len,
           float* __restrict__ nll_out) {
  const int n = blockIdx.x;
  const int lane = threadIdx.x;
  const int Tn = in_len[n];
  const float* g = P + (size_t)n * T_ * LP_;

  // skip exponent bias: 0 if skip transition allowed at l, else SBIAS_
  int sb[8];
#pragma unroll
  for (int j = 0; j < 8; ++j) {
    int l = lane * 8 + j;
    int b = SBIAS_;
    if ((l & 1) && l >= 3 && l <= 2 * S_) {
      int m = (l - 1) >> 1;
      b = (targets[n * S_ + m] != targets[n * S_ + m - 1]) ? 0 : SBIAS_;
    }
    sb[j] = b;
  }

  float f[8]; int e[8];
#pragma unroll
  for (int j = 0; j < 8; ++j) { f[j] = 0.0f; e[j] = ZMIN_; }
  if (lane == 0) {
    float p0 = g[0], p1 = g[1];
    f[0] = FR_MANT(p0); e[0] = FR_EXP(p0);
    f[1] = FR_MANT(p1); e[1] = FR_EXP(p1);
  }

  const float* gl = g + lane * 8;
  float4 bA[DPF], bB[DPF];
#pragma unroll
  for (int d = 0; d < DPF; ++d) {
    int tt = 1 + d; if (tt > T_ - 1) tt = T_ - 1;
    bA[d] = *reinterpret_cast<const float4*>(gl + (size_t)tt * LP_);
    bB[d] = *reinterpret_cast<const float4*>(gl + (size_t)tt * LP_ + 4);
  }

  const int src = (lane + 63) & 63;

  auto step = [&](const float4& A, const float4& B) {
    float f7 = __shfl(f[7], src), f6 = __shfl(f[6], src);
    int   e7 = __shfl(e[7], src), e6 = __shfl(e[6], src);
    // lane 0 has no predecessor: kill the wrap path (R1 lesson)
    if (lane == 0) { f7 = 0.0f; f6 = 0.0f; e7 = ZMIN_; e6 = ZMIN_; }
    float pv[8] = {A.x, A.y, A.z, A.w, B.x, B.y, B.z, B.w};
    float nf[8]; int ne[8];
#pragma unroll
    for (int j = 0; j < 8; ++j) {
      float fm1 = (j >= 1) ? f[j - 1] : f7;
      int   em1 = (j >= 1) ? e[j - 1] : e7;
      float fm2 = (j >= 2) ? f[j - 2] : ((j == 1) ? f7 : f6);
      int   em2 = (j >= 2) ? e[j - 2] : ((j == 1) ? e7 : e6);
      int e2b = em2 + sb[j];
      int me = max(max(e[j], em1), e2b);   // v_max3_i32
      float r = LDEXP(f[j], e[j] - me) + LDEXP(fm1, em1 - me)
              + LDEXP(fm2, e2b - me);
      r *= pv[j];
      nf[j] = FR_MANT(r);
      ne[j] = me + FR_EXP(r);              // r==0 -> me stays ~ZMIN_ (all-zero inputs)
    }
#pragma unroll
    for (int j = 0; j < 8; ++j) { f[j] = nf[j]; e[j] = ne[j]; }
  };

  int t = 1;
  const int nsteps = Tn - 1;
  const int nfull = (nsteps / DPF) * DPF;
  for (int s = 0; s < nfull; s += DPF) {
#pragma unroll
    for (int d = 0; d < DPF; ++d) {
      step(bA[d], bB[d]);
      int tt = t + DPF; if (tt > T_ - 1) tt = T_ - 1;
      bA[d] = *reinterpret_cast<const float4*>(gl + (size_t)tt * LP_);
      bB[d] = *reinterpret_cast<const float4*>(gl + (size_t)tt * LP_ + 4);
      ++t;
    }
  }
#pragma unroll
  for (int d = 0; d < DPF - 1; ++d) {
    if (t < Tn) { step(bA[d], bB[d]); ++t; }
  }

  __shared__ float sf[LP_];
  __shared__ int   se[LP_];
#pragma unroll
  for (int j = 0; j < 8; ++j) { sf[lane * 8 + j] = f[j]; se[lane * 8 + j] = e[j]; }
  __syncthreads();
  if (lane == 0) {
    int tl = tgt_len[n];
    float f1 = sf[2 * tl - 1]; int e1 = se[2 * tl - 1];
    float f2 = sf[2 * tl];     int e2 = se[2 * tl];
    int me = max(e1, e2);
    float r = LDEXP(f1, e1 - me) + LDEXP(f2, e2 - me);
    nll_out[n] = -LN2_ * ((float)me + LOG2(r));
  }
}

__global__ void k_final(const float* __restrict__ nll,
                        const int* __restrict__ tgt_len,
                        float* __restrict__ out) {
  int lane = threadIdx.x;
  float v = 0.0f;
  if (lane < N_) v = nll[lane] / (float)tgt_len[lane];
#pragma unroll
  for (int i = 1; i < 64; i <<= 1) v += __shfl_xor(v, i);
  if (lane == 0) out[0] = v * (1.0f / N_);
}

__global__ void k_sentinel(float* out) { out[0] = -12345.0f; }

extern "C" void kernel_launch(void* const* d_in, const int* in_sizes, int n_in,
                              void* d_out, int out_size, void* d_ws, size_t ws_size,
                              hipStream_t stream) {
  const float* logits = (const float*)d_in[0];
  const int* targets  = (const int*)d_in[1];
  const int* in_len   = (const int*)d_in[2];
  const int* tgt_len  = (const int*)d_in[3];
  float* out = (float*)d_out;

  size_t gbytes = (size_t)N_ * T_ * LP_ * sizeof(float);  // ~104.9 MB
  if (ws_size < gbytes + 256) {
    k_sentinel<<<1, 1, 0, stream>>>(out);
    return;
  }
  float* G = (float*)d_ws;
  float* nll = (float*)((char*)d_ws + gbytes);

  k_softmax_gather<<<(N_ * T_) / 4, 256, 0, stream>>>(logits, targets, G);
  k_ctc<<<N_, 64, 0, stream>>>(G, targets, in_len, tgt_len, nll);
  k_final<<<1, 64, 0, stream>>>(nll, tgt_len, out);
}

// Round 4
// 493.543 us; speedup vs baseline: 1.5531x; 1.3955x over previous
//
#include <hip/hip_runtime.h>
#include <hip/hip_bf16.h>

#define N_    32
#define T_    1600
#define C_    1024
#define S_    200
#define L_    401       // 2*S+1
#define LP_   512       // padded to 64*8
#define BLANK_ 4
#define LN2_  0.69314718055994531f
#define L2E_  1.44269504088896341f
#define DPF   8

#if __has_builtin(__builtin_amdgcn_exp2f)
#define EXP2(x) __builtin_amdgcn_exp2f(x)
#else
#define EXP2(x) exp2f(x)
#endif
#if __has_builtin(__builtin_amdgcn_rcpf)
#define RCP(x) __builtin_amdgcn_rcpf(x)
#else
#define RCP(x) (1.0f / (x))
#endif

// Kernel 1: one wave per (n,t) row. Wave-shuffle softmax, row staged in LDS,
// gather ext-label classes, write LINEAR probabilities P[n][t][l].
// Junk positions (l > 2*tgt_len[n], never read; transitions are monotone in l)
// are zeroed so they can't pollute the wave-max renorm scale in k_ctc.
__global__ __launch_bounds__(256)
void k_softmax_gather(const float* __restrict__ logits,
                      const int* __restrict__ targets,
                      const int* __restrict__ tgt_len,
                      float* __restrict__ P) {
  const int row  = blockIdx.x * 4 + (threadIdx.x >> 6);  // n*T_ + t
  const int lane = threadIdx.x & 63;
  const int wv   = threadIdx.x >> 6;
  const int n    = row / T_;
  const float* x = logits + (size_t)row * C_;
  __shared__ float sh[4][C_];

  float4 v[4];
#pragma unroll
  for (int i = 0; i < 4; ++i)
    v[i] = reinterpret_cast<const float4*>(x)[i * 64 + lane];

  float mx = v[0].x;
#pragma unroll
  for (int i = 0; i < 4; ++i)
    mx = fmaxf(mx, fmaxf(fmaxf(v[i].x, v[i].y), fmaxf(v[i].z, v[i].w)));
#pragma unroll
  for (int i = 1; i < 64; i <<= 1) mx = fmaxf(mx, __shfl_xor(mx, i));

  float s = 0.0f;
#pragma unroll
  for (int i = 0; i < 4; ++i) {
    s += EXP2((v[i].x - mx) * L2E_) + EXP2((v[i].y - mx) * L2E_)
       + EXP2((v[i].z - mx) * L2E_) + EXP2((v[i].w - mx) * L2E_);
  }
#pragma unroll
  for (int i = 1; i < 64; i <<= 1) s += __shfl_xor(s, i);
  float rz = RCP(s);

#pragma unroll
  for (int i = 0; i < 4; ++i)
    reinterpret_cast<float4*>(sh[wv])[i * 64 + lane] = v[i];
  __syncthreads();

  const int* tg = targets + n * S_;
  const int lmax = 2 * tgt_len[n];   // live region is l in [0, 2*tl]
  float* out = P + (size_t)row * LP_;
#pragma unroll
  for (int i = 0; i < 8; ++i) {
    int l = lane + i * 64;
    float p = 0.0f;
    if (l <= lmax) {                 // lmax <= 400 < L_ always
      int c = (l & 1) ? tg[(l - 1) >> 1] : BLANK_;
      p = EXP2((sh[wv][c] - mx) * L2E_) * rz;
    }
    out[l] = p;
  }
}

// Kernel 2: CTC forward in raw f64 linear space. Per position per step:
// a = (a + a_m1 + sk*a_m2) * p  -> v_add_f64 + v_fma_f64 + v_mul_f64.
// Wave-uniform renorm by 2^R every 32 steps (R from int-hi-word wave max;
// positive-double hi words are order-isomorphic to the values).
__global__ __launch_bounds__(64)
void k_ctc(const float* __restrict__ P,
           const int* __restrict__ targets,
           const int* __restrict__ in_len,
           const int* __restrict__ tgt_len,
           float* __restrict__ nll_out) {
  const int n = blockIdx.x;
  const int lane = threadIdx.x;
  const int Tn = in_len[n];
  const float* g = P + (size_t)n * T_ * LP_;

  // skip multiplier: 1.0 iff odd l, l>=3, l<=2S, labels differ
  double sk[8];
#pragma unroll
  for (int j = 0; j < 8; ++j) {
    int l = lane * 8 + j;
    double b = 0.0;
    if ((l & 1) && l >= 3 && l <= 2 * S_) {
      int m = (l - 1) >> 1;
      b = (targets[n * S_ + m] != targets[n * S_ + m - 1]) ? 1.0 : 0.0;
    }
    sk[j] = b;
  }

  double a[8];
#pragma unroll
  for (int j = 0; j < 8; ++j) a[j] = 0.0;
  if (lane == 0) { a[0] = (double)g[0]; a[1] = (double)g[1]; }
  int Etot = 0;  // true alpha = a * 2^Etot (wave-uniform)

  const float* gl = g + lane * 8;
  float4 bA[DPF], bB[DPF];
#pragma unroll
  for (int d = 0; d < DPF; ++d) {
    int tt = 1 + d; if (tt > T_ - 1) tt = T_ - 1;
    bA[d] = *reinterpret_cast<const float4*>(gl + (size_t)tt * LP_);
    bB[d] = *reinterpret_cast<const float4*>(gl + (size_t)tt * LP_ + 4);
  }

  const int src = (lane + 63) & 63;

  auto step = [&](const float4& A, const float4& B) {
    double up7 = __shfl(a[7], src);   // alpha[l-1] for j=0
    double up6 = __shfl(a[6], src);   // alpha[l-2] for j=0
    if (lane == 0) { up7 = 0.0; up6 = 0.0; }  // no predecessor (R1 lesson)
    float pv[8] = {A.x, A.y, A.z, A.w, B.x, B.y, B.z, B.w};
    // in-place descending: a[j] uses old a[j-1], a[j-2] (not yet overwritten)
#pragma unroll
    for (int j = 7; j >= 2; --j)
      a[j] = (a[j] + a[j - 1] + sk[j] * a[j - 2]) * (double)pv[j];
    a[1] = (a[1] + a[0] + sk[1] * up7) * (double)pv[1];
    a[0] = (a[0] + up7 + sk[0] * up6) * (double)pv[0];   // sk[0]==0 always
  };

  auto renorm = [&]() {
    int h = __double2hiint(a[0]);
#pragma unroll
    for (int j = 1; j < 8; ++j) h = max(h, __double2hiint(a[j]));
#pragma unroll
    for (int i = 1; i < 64; i <<= 1) h = max(h, __shfl_xor(h, i));
    int R = 1021 - (h >> 20);   // scale wave max into [2^-2, 2^-1)
#pragma unroll
    for (int j = 0; j < 8; ++j) a[j] = ldexp(a[j], R);
    Etot -= R;
  };

  int t = 1;
  const int nsteps = Tn - 1;
  const int nfull = (nsteps / DPF) * DPF;
  int blk = 0;
  for (int s = 0; s < nfull; s += DPF) {
#pragma unroll
    for (int d = 0; d < DPF; ++d) {
      step(bA[d], bB[d]);
      int tt = t + DPF; if (tt > T_ - 1) tt = T_ - 1;
      bA[d] = *reinterpret_cast<const float4*>(gl + (size_t)tt * LP_);
      bB[d] = *reinterpret_cast<const float4*>(gl + (size_t)tt * LP_ + 4);
      ++t;
    }
    if ((++blk & 3) == 0) renorm();   // every 32 steps; max gap 39 < f64 range
  }
#pragma unroll
  for (int d = 0; d < DPF - 1; ++d) {
    if (t < Tn) { step(bA[d], bB[d]); ++t; }
  }

  __shared__ double sa[LP_];
#pragma unroll
  for (int j = 0; j < 8; ++j) sa[lane * 8 + j] = a[j];
  __syncthreads();
  if (lane == 0) {
    int tl = tgt_len[n];
    double v = sa[2 * tl - 1] + sa[2 * tl];
    int ee;
    double m = frexp(v, &ee);   // v>0 always (readout positions live)
    nll_out[n] = -LN2_ * ((float)(Etot + ee) + log2f((float)m));
  }
}

__global__ void k_final(const float* __restrict__ nll,
                        const int* __restrict__ tgt_len,
                        float* __restrict__ out) {
  int lane = threadIdx.x;
  float v = 0.0f;
  if (lane < N_) v = nll[lane] / (float)tgt_len[lane];
#pragma unroll
  for (int i = 1; i < 64; i <<= 1) v += __shfl_xor(v, i);
  if (lane == 0) out[0] = v * (1.0f / N_);
}

__global__ void k_sentinel(float* out) { out[0] = -12345.0f; }

extern "C" void kernel_launch(void* const* d_in, const int* in_sizes, int n_in,
                              void* d_out, int out_size, void* d_ws, size_t ws_size,
                              hipStream_t stream) {
  const float* logits = (const float*)d_in[0];
  const int* targets  = (const int*)d_in[1];
  const int* in_len   = (const int*)d_in[2];
  const int* tgt_len  = (const int*)d_in[3];
  float* out = (float*)d_out;

  size_t gbytes = (size_t)N_ * T_ * LP_ * sizeof(float);  // ~104.9 MB
  if (ws_size < gbytes + 256) {
    k_sentinel<<<1, 1, 0, stream>>>(out);
    return;
  }
  float* G = (float*)d_ws;
  float* nll = (float*)((char*)d_ws + gbytes);

  k_softmax_gather<<<(N_ * T_) / 4, 256, 0, stream>>>(logits, targets, tgt_len, G);
  k_ctc<<<N_, 64, 0, stream>>>(G, targets, in_len, tgt_len, nll);
  k_final<<<1, 64, 0, stream>>>(nll, tgt_len, out);
}